// Round 2
// baseline (1701.784 us; speedup 1.0000x reference)
//
#include <hip/hip_runtime.h>

#define NFEAT 128
#define NCLS  64
#define CPB   192      // destination cols per bucket (col_local fits in 8 bits)
#define NBMAX 1024
#define PCHUNK 4096

// ---------------- P1: bucket histogram (LDS-privatized) ----------------
__global__ __launch_bounds__(256) void hist_k(const int* __restrict__ col, int E,
                                              int* __restrict__ bhist, int NB) {
    __shared__ int h[NBMAX];
    for (int i = threadIdx.x; i < NB; i += 256) h[i] = 0;
    __syncthreads();
    int stride = gridDim.x * 256;
    for (int e = blockIdx.x * 256 + threadIdx.x; e < E; e += stride)
        atomicAdd(&h[col[e] / CPB], 1);
    __syncthreads();
    for (int i = threadIdx.x; i < NB; i += 256)
        if (h[i]) atomicAdd(&bhist[i], h[i]);
}

// ---------------- P2: exclusive scan of bucket counts (single block) ----------------
__global__ __launch_bounds__(1024) void scan_k(const int* __restrict__ bhist,
                                               int* __restrict__ bptr,
                                               int* __restrict__ bcursor, int NB, int E) {
    __shared__ int s[1024];
    int t = threadIdx.x;
    int v = (t < NB) ? bhist[t] : 0;
    s[t] = v;
    for (int off = 1; off < 1024; off <<= 1) {
        __syncthreads();
        int a = (t >= off) ? s[t - off] : 0;
        __syncthreads();
        s[t] += a;
    }
    if (t < NB) { int p = s[t] - v; bptr[t] = p; bcursor[t] = p; }
    if (t == 0) bptr[NB] = E;
}

// ---------------- P3: chunk-aggregated partition scatter ----------------
// One global atomic per (block,bucket) to reserve a range; per-edge positions via LDS
// atomics. Writes for one (chunk,bucket) are contiguous -> write-back coalesces.
__global__ __launch_bounds__(256) void part_k(const int* __restrict__ row,
                                              const int* __restrict__ col, int E,
                                              int* __restrict__ bcursor,
                                              int* __restrict__ ebuf, int NB) {
    __shared__ int h[NBMAX];
    __shared__ int cur[NBMAX];
    int t = threadIdx.x;
    int start = blockIdx.x * PCHUNK;
    int end   = min(start + PCHUNK, E);
    for (int i = t; i < NB; i += 256) h[i] = 0;
    __syncthreads();
    for (int e = start + t; e < end; e += 256)
        atomicAdd(&h[col[e] / CPB], 1);
    __syncthreads();
    for (int i = t; i < NB; i += 256)
        cur[i] = h[i] ? atomicAdd(&bcursor[i], h[i]) : 0;
    __syncthreads();
    for (int e = start + t; e < end; e += 256) {
        int c = col[e], b = c / CPB, cl = c - b * CPB;
        int pos = atomicAdd(&cur[b], 1);
        ebuf[pos] = row[e] | (cl << 17);   // row < 2^17, cl < 2^8
    }
}

// ---------------- P4: degree -> dinv (per-bucket LDS histogram, no global atomics) ----
__global__ __launch_bounds__(256) void deg_k(const int* __restrict__ ebuf,
                                             const int* __restrict__ bptr,
                                             float* __restrict__ dinv, int N) {
    __shared__ int h[CPB];
    int b = blockIdx.x, t = threadIdx.x;
    for (int i = t; i < CPB; i += 256) h[i] = 0;
    __syncthreads();
    int s = bptr[b], e = bptr[b + 1];
    for (int j = s + t; j < e; j += 256)
        atomicAdd(&h[ebuf[j] >> 17], 1);
    __syncthreads();
    int c0 = b * CPB;
    for (int i = t; i < CPB; i += 256) {
        int c = c0 + i;
        if (c < N) dinv[c] = rsqrtf((float)(h[i] + 1));   // +1: self-loop
    }
}

// ---------------- projection: y0 = x @ W^T ----------------
__global__ __launch_bounds__(256) void proj_k(const float* __restrict__ x,
                                              const float* __restrict__ W,
                                              float* __restrict__ y, int n) {
    __shared__ float xs[64][132];
    __shared__ float ws[128][68];
    int t = threadIdx.x;
    int nb = blockIdx.x * 64;

    for (int it = 0; it < 8; ++it) {
        int chunk = t + it * 256;
        int c  = chunk >> 5;
        int f4 = (chunk & 31) << 2;
        float4 wv = *reinterpret_cast<const float4*>(&W[c * NFEAT + f4]);
        ws[f4 + 0][c] = wv.x; ws[f4 + 1][c] = wv.y;
        ws[f4 + 2][c] = wv.z; ws[f4 + 3][c] = wv.w;
    }
    for (int it = 0; it < 8; ++it) {
        int chunk = t + it * 256;
        int nloc = chunk >> 5;
        int f4   = (chunk & 31) << 2;
        int g = nb + nloc;
        float4 xv = (g < n) ? *reinterpret_cast<const float4*>(&x[(size_t)g * NFEAT + f4])
                            : make_float4(0.f, 0.f, 0.f, 0.f);
        *reinterpret_cast<float4*>(&xs[nloc][f4]) = xv;
    }
    __syncthreads();

    int tc = t & 15;
    int tn = t >> 4;
    float4 acc[4];
#pragma unroll
    for (int i = 0; i < 4; ++i) acc[i] = make_float4(0.f, 0.f, 0.f, 0.f);

    for (int f4 = 0; f4 < NFEAT; f4 += 4) {
        float4 xv[4], wv[4];
#pragma unroll
        for (int i = 0; i < 4; ++i)
            xv[i] = *reinterpret_cast<const float4*>(&xs[tn + 16 * i][f4]);
#pragma unroll
        for (int k = 0; k < 4; ++k)
            wv[k] = *reinterpret_cast<const float4*>(&ws[f4 + k][tc * 4]);
#pragma unroll
        for (int i = 0; i < 4; ++i) {
            acc[i].x += xv[i].x * wv[0].x + xv[i].y * wv[1].x + xv[i].z * wv[2].x + xv[i].w * wv[3].x;
            acc[i].y += xv[i].x * wv[0].y + xv[i].y * wv[1].y + xv[i].z * wv[2].y + xv[i].w * wv[3].y;
            acc[i].z += xv[i].x * wv[0].z + xv[i].y * wv[1].z + xv[i].z * wv[2].z + xv[i].w * wv[3].z;
            acc[i].w += xv[i].x * wv[0].w + xv[i].y * wv[1].w + xv[i].z * wv[2].w + xv[i].w * wv[3].w;
        }
    }
#pragma unroll
    for (int i = 0; i < 4; ++i) {
        int g = nb + tn + 16 * i;
        if (g < n)
            *reinterpret_cast<float4*>(&y[(size_t)g * NCLS + tc * 4]) = acc[i];
    }
}

// ---------------- P5: per-bucket LDS-accumulate SpMM ----------------
// Block b owns cols [b*CPB, (b+1)*CPB). 48KB LDS accumulator; edges streamed with
// wave-uniform scalar entry loads + 4-wide pipelined 256B gathers; fused self-loop,
// dinv scale, bias.
template <bool BIAS>
__global__ __launch_bounds__(512) void spmm_k(const float* __restrict__ yin,
                                              float* __restrict__ yout,
                                              const int* __restrict__ ebuf,
                                              const int* __restrict__ bptr,
                                              const float* __restrict__ dinv,
                                              const float* __restrict__ bias, int N) {
    __shared__ float acc[CPB][NCLS];
    int t = threadIdx.x;
    float4* af = (float4*)&acc[0][0];
    for (int i = t; i < CPB * NCLS / 4; i += 512) af[i] = make_float4(0.f, 0.f, 0.f, 0.f);
    __syncthreads();

    int b = blockIdx.x;
    int s = bptr[b], e = bptr[b + 1];
    int lane = t & 63, w = t >> 6;   // 8 waves, wave-strided over edges

    int j = s + w;
    for (; j + 24 < e; j += 32) {
        int p0 = ebuf[j], p1 = ebuf[j + 8], p2 = ebuf[j + 16], p3 = ebuf[j + 24];
        int r0 = p0 & 0x1FFFF, r1 = p1 & 0x1FFFF, r2 = p2 & 0x1FFFF, r3 = p3 & 0x1FFFF;
        float g0 = yin[(size_t)r0 * NCLS + lane];
        float g1 = yin[(size_t)r1 * NCLS + lane];
        float g2 = yin[(size_t)r2 * NCLS + lane];
        float g3 = yin[(size_t)r3 * NCLS + lane];
        atomicAdd(&acc[p0 >> 17][lane], dinv[r0] * g0);
        atomicAdd(&acc[p1 >> 17][lane], dinv[r1] * g1);
        atomicAdd(&acc[p2 >> 17][lane], dinv[r2] * g2);
        atomicAdd(&acc[p3 >> 17][lane], dinv[r3] * g3);
    }
    for (; j < e; j += 8) {
        int p = ebuf[j]; int r = p & 0x1FFFF;
        atomicAdd(&acc[p >> 17][lane], dinv[r] * yin[(size_t)r * NCLS + lane]);
    }
    __syncthreads();

    int c0 = b * CPB;
    for (int cl = w; cl < CPB; cl += 8) {
        int c = c0 + cl;
        if (c < N) {
            float d = dinv[c];
            float o = d * (acc[cl][lane] + d * yin[(size_t)c * NCLS + lane]);
            if (BIAS) o += bias[lane];
            yout[(size_t)c * NCLS + lane] = o;
        }
    }
}

// ---------------- launch ----------------
extern "C" void kernel_launch(void* const* d_in, const int* in_sizes, int n_in,
                              void* d_out, int out_size, void* d_ws, size_t ws_size,
                              hipStream_t stream) {
    const float* x  = (const float*)d_in[0];
    const int*   ei = (const int*)d_in[1];
    const float* W  = (const float*)d_in[2];
    const float* b  = (const float*)d_in[3];
    float* out = (float*)d_out;

    const int N = in_sizes[0] / NFEAT;   // 100000
    const int E = in_sizes[1] / 2;       // 1600000
    const int* row = ei;
    const int* col = ei + E;
    const int NB = (N + CPB - 1) / CPB;  // 521
    if (NB + 1 > NBMAX) return;

    // workspace layout
    float* y0      = (float*)d_ws;                  // N*64
    float* y1      = y0 + (size_t)N * NCLS;         // N*64
    int*   ebuf    = (int*)(y1 + (size_t)N * NCLS); // E
    float* dinv    = (float*)(ebuf + E);            // N
    int*   bhist   = (int*)(dinv + N);              // NB
    int*   bptr    = bhist + NB;                    // NB+1
    int*   bcursor = bptr + NB + 1;                 // NB

    size_t needed = ((size_t)N * NCLS * 2 + (size_t)E + (size_t)N + 3 * (size_t)NB + 1) * 4;
    if (ws_size < needed) return;

    hipMemsetAsync(bhist, 0, (size_t)NB * 4, stream);
    hist_k<<<256, 256, 0, stream>>>(col, E, bhist, NB);
    scan_k<<<1, 1024, 0, stream>>>(bhist, bptr, bcursor, NB, E);
    part_k<<<(E + PCHUNK - 1) / PCHUNK, 256, 0, stream>>>(row, col, E, bcursor, ebuf, NB);
    deg_k<<<NB, 256, 0, stream>>>(ebuf, bptr, dinv, N);

    proj_k<<<(N + 63) / 64, 256, 0, stream>>>(x, W, y0, N);

    spmm_k<false><<<NB, 512, 0, stream>>>(y0, y1, ebuf, bptr, dinv, b, N);
    spmm_k<true ><<<NB, 512, 0, stream>>>(y1, out, ebuf, bptr, dinv, b, N);
}

// Round 3
// 335.165 us; speedup vs baseline: 5.0774x; 5.0774x over previous
//
#include <hip/hip_runtime.h>

#define NFEAT 128
#define NCLS  64
#define CPB   192      // destination cols per bucket (col_local fits in bits 17..24)
#define NBMAX 1024
#define PCHUNK 8192

// ---------------- P1: bucket histogram (LDS-privatized) ----------------
__global__ __launch_bounds__(256) void hist_k(const int* __restrict__ col, int E,
                                              int* __restrict__ bhist, int NB) {
    __shared__ int h[NBMAX];
    for (int i = threadIdx.x; i < NB; i += 256) h[i] = 0;
    __syncthreads();
    int stride = gridDim.x * 256;
    for (int e = blockIdx.x * 256 + threadIdx.x; e < E; e += stride)
        atomicAdd(&h[col[e] / CPB], 1);
    __syncthreads();
    for (int i = threadIdx.x; i < NB; i += 256)
        if (h[i]) atomicAdd(&bhist[i], h[i]);
}

// ---------------- P2: exclusive scan of bucket counts (single block) ----------------
__global__ __launch_bounds__(1024) void scan_k(const int* __restrict__ bhist,
                                               int* __restrict__ bptr,
                                               int* __restrict__ bcursor, int NB, int E) {
    __shared__ int s[1024];
    int t = threadIdx.x;
    int v = (t < NB) ? bhist[t] : 0;
    s[t] = v;
    for (int off = 1; off < 1024; off <<= 1) {
        __syncthreads();
        int a = (t >= off) ? s[t - off] : 0;
        __syncthreads();
        s[t] += a;
    }
    if (t < NB) { int p = s[t] - v; bptr[t] = p; bcursor[t] = p; }
    if (t == 0) bptr[NB] = E;
}

// ---------------- P3: chunk-aggregated partition scatter ----------------
// One global atomic per (block,bucket); per-edge positions via LDS cursors. Writes for
// one (chunk,bucket) are contiguous runs (~16 x 4B) -> write-back coalesces.
__global__ __launch_bounds__(256) void part_k(const int* __restrict__ row,
                                              const int* __restrict__ col, int E,
                                              int* __restrict__ bcursor,
                                              int* __restrict__ ebuf, int NB) {
    __shared__ int h[NBMAX];
    __shared__ int cur[NBMAX];
    int t = threadIdx.x;
    int start = blockIdx.x * PCHUNK;
    int end   = min(start + PCHUNK, E);
    for (int i = t; i < NB; i += 256) h[i] = 0;
    __syncthreads();
    for (int e = start + t; e < end; e += 256)
        atomicAdd(&h[col[e] / CPB], 1);
    __syncthreads();
    for (int i = t; i < NB; i += 256)
        cur[i] = h[i] ? atomicAdd(&bcursor[i], h[i]) : 0;
    __syncthreads();
    for (int e = start + t; e < end; e += 256) {
        int c = col[e], b = c / CPB, cl = c - b * CPB;
        int pos = atomicAdd(&cur[b], 1);
        ebuf[pos] = row[e] | (cl << 17);   // row < 2^17, cl < 2^8
    }
}

// ---------------- P4: degree -> dinv (per-bucket LDS histogram) ----------------
__global__ __launch_bounds__(256) void deg_k(const int* __restrict__ ebuf,
                                             const int* __restrict__ bptr,
                                             float* __restrict__ dinv, int N) {
    __shared__ int h[CPB];
    int b = blockIdx.x, t = threadIdx.x;
    for (int i = t; i < CPB; i += 256) h[i] = 0;
    __syncthreads();
    int s = bptr[b], e = bptr[b + 1];
    for (int j = s + t; j < e; j += 256)
        atomicAdd(&h[ebuf[j] >> 17], 1);
    __syncthreads();
    int c0 = b * CPB;
    for (int i = t; i < CPB; i += 256) {
        int c = c0 + i;
        if (c < N) dinv[c] = rsqrtf((float)(h[i] + 1));   // +1: self-loop
    }
}

// ---------------- P5: within-bucket counting sort -> full per-node CSR ----------------
// Block per bucket: LDS hist(192) + scan -> per-node ptr/cnt; scatter {row, dinv[row]}
// into the bucket's contiguous csr window (24KB -> L2 write-coalesced). No LDS staging,
// safe for any bucket size.
__global__ __launch_bounds__(256) void sort_k(const int* __restrict__ ebuf,
                                              const int* __restrict__ bptr,
                                              const float* __restrict__ dinv,
                                              int* __restrict__ ptrv, int* __restrict__ cnt,
                                              int2* __restrict__ csr, int N) {
    __shared__ int h[CPB];
    __shared__ int cur[CPB];
    __shared__ int sc[256];
    int b = blockIdx.x, t = threadIdx.x;
    for (int i = t; i < CPB; i += 256) h[i] = 0;
    __syncthreads();
    int s = bptr[b], e = bptr[b + 1];
    for (int j = s + t; j < e; j += 256)
        atomicAdd(&h[ebuf[j] >> 17], 1);
    __syncthreads();
    int v = (t < CPB) ? h[t] : 0;
    sc[t] = v;
    for (int off = 1; off < 256; off <<= 1) {
        __syncthreads();
        int a = (t >= off) ? sc[t - off] : 0;
        __syncthreads();
        sc[t] += a;
    }
    __syncthreads();
    if (t < CPB) {
        int c = b * CPB + t;
        int p = s + sc[t] - v;     // exclusive prefix within bucket
        cur[t] = p;
        if (c < N) { ptrv[c] = p; cnt[c] = v; }
    }
    __syncthreads();
    for (int j = s + t; j < e; j += 256) {
        int p = ebuf[j];
        int r = p & 0x1FFFF, cl = p >> 17;
        int pos = atomicAdd(&cur[cl], 1);
        csr[pos] = make_int2(r, __float_as_int(dinv[r]));
    }
}

// ---------------- projection: y0 = x @ W^T ----------------
__global__ __launch_bounds__(256) void proj_k(const float* __restrict__ x,
                                              const float* __restrict__ W,
                                              float* __restrict__ y, int n) {
    __shared__ float xs[64][132];
    __shared__ float ws[128][68];
    int t = threadIdx.x;
    int nb = blockIdx.x * 64;

    for (int it = 0; it < 8; ++it) {
        int chunk = t + it * 256;
        int c  = chunk >> 5;
        int f4 = (chunk & 31) << 2;
        float4 wv = *reinterpret_cast<const float4*>(&W[c * NFEAT + f4]);
        ws[f4 + 0][c] = wv.x; ws[f4 + 1][c] = wv.y;
        ws[f4 + 2][c] = wv.z; ws[f4 + 3][c] = wv.w;
    }
    for (int it = 0; it < 8; ++it) {
        int chunk = t + it * 256;
        int nloc = chunk >> 5;
        int f4   = (chunk & 31) << 2;
        int g = nb + nloc;
        float4 xv = (g < n) ? *reinterpret_cast<const float4*>(&x[(size_t)g * NFEAT + f4])
                            : make_float4(0.f, 0.f, 0.f, 0.f);
        *reinterpret_cast<float4*>(&xs[nloc][f4]) = xv;
    }
    __syncthreads();

    int tc = t & 15;
    int tn = t >> 4;
    float4 acc[4];
#pragma unroll
    for (int i = 0; i < 4; ++i) acc[i] = make_float4(0.f, 0.f, 0.f, 0.f);

    for (int f4 = 0; f4 < NFEAT; f4 += 4) {
        float4 xv[4], wv[4];
#pragma unroll
        for (int i = 0; i < 4; ++i)
            xv[i] = *reinterpret_cast<const float4*>(&xs[tn + 16 * i][f4]);
#pragma unroll
        for (int k = 0; k < 4; ++k)
            wv[k] = *reinterpret_cast<const float4*>(&ws[f4 + k][tc * 4]);
#pragma unroll
        for (int i = 0; i < 4; ++i) {
            acc[i].x += xv[i].x * wv[0].x + xv[i].y * wv[1].x + xv[i].z * wv[2].x + xv[i].w * wv[3].x;
            acc[i].y += xv[i].x * wv[0].y + xv[i].y * wv[1].y + xv[i].z * wv[2].y + xv[i].w * wv[3].y;
            acc[i].z += xv[i].x * wv[0].z + xv[i].y * wv[1].z + xv[i].z * wv[2].z + xv[i].w * wv[3].z;
            acc[i].w += xv[i].x * wv[0].w + xv[i].y * wv[1].w + xv[i].z * wv[2].w + xv[i].w * wv[3].w;
        }
    }
#pragma unroll
    for (int i = 0; i < 4; ++i) {
        int g = nb + tn + 16 * i;
        if (g < n)
            *reinterpret_cast<float4*>(&y[(size_t)g * NCLS + tc * 4]) = acc[i];
    }
}

// ---------------- P6: SpMM hop — wave per node, register accumulate ----------------
// lane = class; 4-deep software-pipelined 256B gathers; {row,dinv} packed in csr entry
// so the hot loop has one uniform 8B load + one coalesced 256B gather per edge.
template <bool BIAS>
__global__ __launch_bounds__(256) void spmm_k(const float* __restrict__ yin,
                                              float* __restrict__ yout,
                                              const int* __restrict__ ptrv,
                                              const int* __restrict__ cnt,
                                              const float* __restrict__ dinv,
                                              const int2* __restrict__ csr,
                                              const float* __restrict__ bias, int n) {
    int lane = threadIdx.x & 63;
    int wid  = blockIdx.x * 4 + (threadIdx.x >> 6);
    wid = __builtin_amdgcn_readfirstlane(wid);
    if (wid >= n) return;

    float di = dinv[wid];
    int s = ptrv[wid];
    int e = s + cnt[wid];
    float acc = di * yin[(size_t)wid * NCLS + lane];   // self-loop (×di again below)
    int j = s;
    for (; j + 4 <= e; j += 4) {
        int2 e0 = csr[j], e1 = csr[j + 1], e2 = csr[j + 2], e3 = csr[j + 3];
        float g0 = yin[(size_t)e0.x * NCLS + lane];
        float g1 = yin[(size_t)e1.x * NCLS + lane];
        float g2 = yin[(size_t)e2.x * NCLS + lane];
        float g3 = yin[(size_t)e3.x * NCLS + lane];
        acc = fmaf(__int_as_float(e0.y), g0, acc);
        acc = fmaf(__int_as_float(e1.y), g1, acc);
        acc = fmaf(__int_as_float(e2.y), g2, acc);
        acc = fmaf(__int_as_float(e3.y), g3, acc);
    }
    for (; j < e; ++j) {
        int2 e0 = csr[j];
        acc = fmaf(__int_as_float(e0.y), yin[(size_t)e0.x * NCLS + lane], acc);
    }
    float o = di * acc;
    if (BIAS) o += bias[lane];
    yout[(size_t)wid * NCLS + lane] = o;
}

// ---------------- launch ----------------
extern "C" void kernel_launch(void* const* d_in, const int* in_sizes, int n_in,
                              void* d_out, int out_size, void* d_ws, size_t ws_size,
                              hipStream_t stream) {
    const float* x  = (const float*)d_in[0];
    const int*   ei = (const int*)d_in[1];
    const float* W  = (const float*)d_in[2];
    const float* b  = (const float*)d_in[3];
    float* out = (float*)d_out;

    const int N = in_sizes[0] / NFEAT;   // 100000
    const int E = in_sizes[1] / 2;       // 1600000
    const int* row = ei;
    const int* col = ei + E;
    const int NB = (N + CPB - 1) / CPB;  // 521
    if (NB + 1 > NBMAX) return;

    // workspace layout (csr 8B-aligned: offsets before it are even ints)
    float* y0      = (float*)d_ws;                  // N*64
    float* y1      = y0 + (size_t)N * NCLS;         // N*64
    int*   ebuf    = (int*)(y1 + (size_t)N * NCLS); // E
    int2*  csr     = (int2*)(ebuf + E);             // E int2
    float* dinv    = (float*)(csr + E);             // N
    int*   ptrv    = (int*)(dinv + N);              // N
    int*   cnt     = ptrv + N;                      // N
    int*   bhist   = cnt + N;                       // NB
    int*   bptr    = bhist + NB;                    // NB+1
    int*   bcursor = bptr + NB + 1;                 // NB

    size_t needed = ((size_t)N * NCLS * 2 + (size_t)E * 3 + (size_t)N * 3
                     + 3 * (size_t)NB + 1) * 4;
    if (ws_size < needed) return;

    hipMemsetAsync(bhist, 0, (size_t)NB * 4, stream);
    hist_k<<<256, 256, 0, stream>>>(col, E, bhist, NB);
    scan_k<<<1, 1024, 0, stream>>>(bhist, bptr, bcursor, NB, E);
    part_k<<<(E + PCHUNK - 1) / PCHUNK, 256, 0, stream>>>(row, col, E, bcursor, ebuf, NB);
    deg_k<<<NB, 256, 0, stream>>>(ebuf, bptr, dinv, N);
    sort_k<<<NB, 256, 0, stream>>>(ebuf, bptr, dinv, ptrv, cnt, csr, N);

    proj_k<<<(N + 63) / 64, 256, 0, stream>>>(x, W, y0, N);

    spmm_k<false><<<(N + 3) / 4, 256, 0, stream>>>(y0, y1, ptrv, cnt, dinv, csr, b, N);
    spmm_k<true ><<<(N + 3) / 4, 256, 0, stream>>>(y1, out, ptrv, cnt, dinv, csr, b, N);
}

// Round 4
// 324.267 us; speedup vs baseline: 5.2481x; 1.0336x over previous
//
#include <hip/hip_runtime.h>

#define NFEAT 128
#define NCLS  64
#define CPB   192      // destination cols per bucket (col_local in bits 17..24)
#define NBMAX 1024
#define PCHUNK 8192

// ---------------- P1: bucket histogram (LDS-privatized) ----------------
__global__ __launch_bounds__(256) void hist_k(const int* __restrict__ col, int E,
                                              int* __restrict__ bhist, int NB) {
    __shared__ int h[NBMAX];
    for (int i = threadIdx.x; i < NB; i += 256) h[i] = 0;
    __syncthreads();
    int stride = gridDim.x * 256;
    for (int e = blockIdx.x * 256 + threadIdx.x; e < E; e += stride)
        atomicAdd(&h[col[e] / CPB], 1);
    __syncthreads();
    for (int i = threadIdx.x; i < NB; i += 256)
        if (h[i]) atomicAdd(&bhist[i], h[i]);
}

// ---------------- P2: exclusive scan of bucket counts ----------------
__global__ __launch_bounds__(1024) void scan_k(const int* __restrict__ bhist,
                                               int* __restrict__ bptr,
                                               int* __restrict__ bcursor, int NB, int E) {
    __shared__ int s[1024];
    int t = threadIdx.x;
    int v = (t < NB) ? bhist[t] : 0;
    s[t] = v;
    for (int off = 1; off < 1024; off <<= 1) {
        __syncthreads();
        int a = (t >= off) ? s[t - off] : 0;
        __syncthreads();
        s[t] += a;
    }
    if (t < NB) { int p = s[t] - v; bptr[t] = p; bcursor[t] = p; }
    if (t == 0) bptr[NB] = E;
}

// ---------------- P3: chunk-aggregated partition scatter ----------------
__global__ __launch_bounds__(256) void part_k(const int* __restrict__ row,
                                              const int* __restrict__ col, int E,
                                              int* __restrict__ bcursor,
                                              int* __restrict__ ebuf, int NB) {
    __shared__ int h[NBMAX];
    __shared__ int cur[NBMAX];
    int t = threadIdx.x;
    int start = blockIdx.x * PCHUNK;
    int end   = min(start + PCHUNK, E);
    for (int i = t; i < NB; i += 256) h[i] = 0;
    __syncthreads();
    for (int e = start + t; e < end; e += 256)
        atomicAdd(&h[col[e] / CPB], 1);
    __syncthreads();
    for (int i = t; i < NB; i += 256)
        cur[i] = h[i] ? atomicAdd(&bcursor[i], h[i]) : 0;
    __syncthreads();
    for (int e = start + t; e < end; e += 256) {
        int c = col[e], b = c / CPB, cl = c - b * CPB;
        int pos = atomicAdd(&cur[b], 1);
        ebuf[pos] = row[e] | (cl << 17);   // row < 2^17, cl < 2^8
    }
}

// ---------------- P4: counting sort -> per-node CSR (row-only entries) + dinv ------
// Block per bucket. Histogram doubles as degree -> dinv = rsqrt(deg+1) (deg_k merged).
// csr entries are 4B (row only): the z-rescaled SpMM needs no per-edge dinv.
__global__ __launch_bounds__(256) void sort_k(const int* __restrict__ ebuf,
                                              const int* __restrict__ bptr,
                                              float* __restrict__ dinv,
                                              int* __restrict__ ptrv, int* __restrict__ cnt,
                                              int* __restrict__ csr, int N) {
    __shared__ int h[CPB];
    __shared__ int cur[CPB];
    __shared__ int sc[256];
    int b = blockIdx.x, t = threadIdx.x;
    for (int i = t; i < CPB; i += 256) h[i] = 0;
    __syncthreads();
    int s = bptr[b], e = bptr[b + 1];
    for (int j = s + t; j < e; j += 256)
        atomicAdd(&h[ebuf[j] >> 17], 1);
    __syncthreads();
    int v = (t < CPB) ? h[t] : 0;
    sc[t] = v;
    for (int off = 1; off < 256; off <<= 1) {
        __syncthreads();
        int a = (t >= off) ? sc[t - off] : 0;
        __syncthreads();
        sc[t] += a;
    }
    __syncthreads();
    if (t < CPB) {
        int c = b * CPB + t;
        int p = s + sc[t] - v;
        cur[t] = p;
        if (c < N) {
            ptrv[c] = p; cnt[c] = v;
            dinv[c] = rsqrtf((float)(v + 1));   // +1: self-loop
        }
    }
    __syncthreads();
    for (int j = s + t; j < e; j += 256) {
        int p = ebuf[j];
        int pos = atomicAdd(&cur[p >> 17], 1);
        csr[pos] = p & 0x1FFFF;
    }
}

// ---------------- projection: z0 = dinv ⊙ (x @ W^T) ----------------
__global__ __launch_bounds__(256) void proj_k(const float* __restrict__ x,
                                              const float* __restrict__ W,
                                              const float* __restrict__ dinv,
                                              float* __restrict__ z, int n) {
    __shared__ float xs[64][132];
    __shared__ float ws[128][68];
    int t = threadIdx.x;
    int nb = blockIdx.x * 64;

    for (int it = 0; it < 8; ++it) {
        int chunk = t + it * 256;
        int c  = chunk >> 5;
        int f4 = (chunk & 31) << 2;
        float4 wv = *reinterpret_cast<const float4*>(&W[c * NFEAT + f4]);
        ws[f4 + 0][c] = wv.x; ws[f4 + 1][c] = wv.y;
        ws[f4 + 2][c] = wv.z; ws[f4 + 3][c] = wv.w;
    }
    for (int it = 0; it < 8; ++it) {
        int chunk = t + it * 256;
        int nloc = chunk >> 5;
        int f4   = (chunk & 31) << 2;
        int g = nb + nloc;
        float4 xv = (g < n) ? *reinterpret_cast<const float4*>(&x[(size_t)g * NFEAT + f4])
                            : make_float4(0.f, 0.f, 0.f, 0.f);
        *reinterpret_cast<float4*>(&xs[nloc][f4]) = xv;
    }
    __syncthreads();

    int tc = t & 15;
    int tn = t >> 4;
    float4 acc[4];
#pragma unroll
    for (int i = 0; i < 4; ++i) acc[i] = make_float4(0.f, 0.f, 0.f, 0.f);

    for (int f4 = 0; f4 < NFEAT; f4 += 4) {
        float4 xv[4], wv[4];
#pragma unroll
        for (int i = 0; i < 4; ++i)
            xv[i] = *reinterpret_cast<const float4*>(&xs[tn + 16 * i][f4]);
#pragma unroll
        for (int k = 0; k < 4; ++k)
            wv[k] = *reinterpret_cast<const float4*>(&ws[f4 + k][tc * 4]);
#pragma unroll
        for (int i = 0; i < 4; ++i) {
            acc[i].x += xv[i].x * wv[0].x + xv[i].y * wv[1].x + xv[i].z * wv[2].x + xv[i].w * wv[3].x;
            acc[i].y += xv[i].x * wv[0].y + xv[i].y * wv[1].y + xv[i].z * wv[2].y + xv[i].w * wv[3].y;
            acc[i].z += xv[i].x * wv[0].z + xv[i].y * wv[1].z + xv[i].z * wv[2].z + xv[i].w * wv[3].z;
            acc[i].w += xv[i].x * wv[0].w + xv[i].y * wv[1].w + xv[i].z * wv[2].w + xv[i].w * wv[3].w;
        }
    }
#pragma unroll
    for (int i = 0; i < 4; ++i) {
        int g = nb + tn + 16 * i;
        if (g < n) {
            float d = dinv[g];
            acc[i].x *= d; acc[i].y *= d; acc[i].z *= d; acc[i].w *= d;
            *reinterpret_cast<float4*>(&z[(size_t)g * NCLS + tc * 4]) = acc[i];
        }
    }
}

// ---------------- P5: SpMM hop on z, 4 edges/wave-instruction ----------------
// lane = 16*edge_slot + class_group; each lane gathers float4 (1KB/instr across wave).
// FINAL=0: out = d^2 * (z[c] + sum z[r]);  FINAL=1: out = d*(z1[c]+sum) + bias.
template <int FINAL>
__global__ __launch_bounds__(256) void spmm_k(const float* __restrict__ zin,
                                              float* __restrict__ out,
                                              const int* __restrict__ ptrv,
                                              const int* __restrict__ cnt,
                                              const float* __restrict__ dinv,
                                              const int* __restrict__ csr,
                                              const float* __restrict__ bias, int n) {
    int t = threadIdx.x;
    int lane = t & 63;
    int wid  = blockIdx.x * 4 + (t >> 6);
    wid = __builtin_amdgcn_readfirstlane(wid);
    if (wid >= n) return;

    int sub = lane >> 4;          // edge slot 0..3
    int cg  = (lane & 15) << 2;   // class group base
    int s = ptrv[wid];
    int e = s + cnt[wid];

    float4 acc = make_float4(0.f, 0.f, 0.f, 0.f);
    int j = s;
    for (; j + 8 <= e; j += 8) {                       // 8 edges, 2 gathers in flight
        int r0 = csr[j + sub];
        int r1 = csr[j + 4 + sub];
        float4 g0 = *reinterpret_cast<const float4*>(&zin[(size_t)r0 * NCLS + cg]);
        float4 g1 = *reinterpret_cast<const float4*>(&zin[(size_t)r1 * NCLS + cg]);
        acc.x += g0.x + g1.x; acc.y += g0.y + g1.y;
        acc.z += g0.z + g1.z; acc.w += g0.w + g1.w;
    }
    if (j + 4 <= e) {
        int r0 = csr[j + sub];
        float4 g0 = *reinterpret_cast<const float4*>(&zin[(size_t)r0 * NCLS + cg]);
        acc.x += g0.x; acc.y += g0.y; acc.z += g0.z; acc.w += g0.w;
        j += 4;
    }
    if (j + sub < e) {                                  // 1..3 leftover edges
        int r0 = csr[j + sub];
        float4 g0 = *reinterpret_cast<const float4*>(&zin[(size_t)r0 * NCLS + cg]);
        acc.x += g0.x; acc.y += g0.y; acc.z += g0.z; acc.w += g0.w;
    }
    // reduce the 4 edge slots (lanes differing in bits 4,5)
    acc.x += __shfl_xor(acc.x, 16, 64); acc.x += __shfl_xor(acc.x, 32, 64);
    acc.y += __shfl_xor(acc.y, 16, 64); acc.y += __shfl_xor(acc.y, 32, 64);
    acc.z += __shfl_xor(acc.z, 16, 64); acc.z += __shfl_xor(acc.z, 32, 64);
    acc.w += __shfl_xor(acc.w, 16, 64); acc.w += __shfl_xor(acc.w, 32, 64);

    float4 self = *reinterpret_cast<const float4*>(&zin[(size_t)wid * NCLS + cg]);
    float d = dinv[wid];
    float4 o;
    if (FINAL) {
        float4 bb = *reinterpret_cast<const float4*>(&bias[cg]);
        o.x = fmaf(d, acc.x + self.x, bb.x);
        o.y = fmaf(d, acc.y + self.y, bb.y);
        o.z = fmaf(d, acc.z + self.z, bb.z);
        o.w = fmaf(d, acc.w + self.w, bb.w);
    } else {
        float d2 = d * d;
        o.x = d2 * (acc.x + self.x);
        o.y = d2 * (acc.y + self.y);
        o.z = d2 * (acc.z + self.z);
        o.w = d2 * (acc.w + self.w);
    }
    if (sub == 0)
        *reinterpret_cast<float4*>(&out[(size_t)wid * NCLS + cg]) = o;
}

// ---------------- launch ----------------
extern "C" void kernel_launch(void* const* d_in, const int* in_sizes, int n_in,
                              void* d_out, int out_size, void* d_ws, size_t ws_size,
                              hipStream_t stream) {
    const float* x  = (const float*)d_in[0];
    const int*   ei = (const int*)d_in[1];
    const float* W  = (const float*)d_in[2];
    const float* b  = (const float*)d_in[3];
    float* out = (float*)d_out;

    const int N = in_sizes[0] / NFEAT;   // 100000
    const int E = in_sizes[1] / 2;       // 1600000
    const int* row = ei;
    const int* col = ei + E;
    const int NB = (N + CPB - 1) / CPB;  // 521
    if (NB + 1 > NBMAX) return;

    // workspace layout
    float* z0      = (float*)d_ws;                  // N*64
    float* z1      = z0 + (size_t)N * NCLS;         // N*64
    int*   ebuf    = (int*)(z1 + (size_t)N * NCLS); // E
    int*   csr     = ebuf + E;                      // E
    float* dinv    = (float*)(csr + E);             // N
    int*   ptrv    = (int*)(dinv + N);              // N
    int*   cnt     = ptrv + N;                      // N
    int*   bhist   = cnt + N;                       // NB
    int*   bptr    = bhist + NB;                    // NB+1
    int*   bcursor = bptr + NB + 1;                 // NB

    size_t needed = ((size_t)N * NCLS * 2 + (size_t)E * 2 + (size_t)N * 3
                     + 3 * (size_t)NB + 1) * 4;
    if (ws_size < needed) return;

    hipMemsetAsync(bhist, 0, (size_t)NB * 4, stream);
    hist_k<<<256, 256, 0, stream>>>(col, E, bhist, NB);
    scan_k<<<1, 1024, 0, stream>>>(bhist, bptr, bcursor, NB, E);
    part_k<<<(E + PCHUNK - 1) / PCHUNK, 256, 0, stream>>>(row, col, E, bcursor, ebuf, NB);
    sort_k<<<NB, 256, 0, stream>>>(ebuf, bptr, dinv, ptrv, cnt, csr, N);

    proj_k<<<(N + 63) / 64, 256, 0, stream>>>(x, W, dinv, z0, N);

    spmm_k<0><<<(N + 3) / 4, 256, 0, stream>>>(z0, z1, ptrv, cnt, dinv, csr, b, N);
    spmm_k<1><<<(N + 3) / 4, 256, 0, stream>>>(z1, out, ptrv, cnt, dinv, csr, b, N);
}

// Round 5
// 290.587 us; speedup vs baseline: 5.8564x; 1.1159x over previous
//
#include <hip/hip_runtime.h>
#include <hip/hip_fp16.h>

#define NFEAT 128
#define NCLS  64
#define CPB   192      // destination cols per bucket (col_local in bits 17..24)
#define NBMAX 1024
#define PCHUNK 8192
#define HGRID 256

// ---------------- P1: bucket histogram + fused bucket scan (last-block pattern) ----
__global__ __launch_bounds__(256) void hist_k(const int* __restrict__ col, int E,
                                              int* __restrict__ bhist,
                                              int* __restrict__ done,
                                              int* __restrict__ bptr,
                                              int* __restrict__ bcursor, int NB) {
    __shared__ int h[NBMAX];
    __shared__ int sc[256];
    __shared__ int lastf;
    int t = threadIdx.x;
    for (int i = t; i < NB; i += 256) h[i] = 0;
    __syncthreads();
    int stride = gridDim.x * 256;
    for (int e = blockIdx.x * 256 + t; e < E; e += stride)
        atomicAdd(&h[col[e] / CPB], 1);
    __syncthreads();
    for (int i = t; i < NB; i += 256)
        if (h[i]) atomicAdd(&bhist[i], h[i]);
    __threadfence();
    if (t == 0) {
        int old = atomicAdd(done, 1);
        lastf = (old == HGRID - 1);
    }
    __syncthreads();
    if (!lastf) return;

    // last block: exclusive scan of bhist[0..NB) -> bptr, bcursor; bptr[NB]=E
    int v[4]; int base = t * 4;
#pragma unroll
    for (int k = 0; k < 4; ++k) {
        int i = base + k;
        v[k] = (i < NB) ? bhist[i] : 0;
    }
    int tot = v[0] + v[1] + v[2] + v[3];
    sc[t] = tot;
    for (int off = 1; off < 256; off <<= 1) {
        __syncthreads();
        int a = (t >= off) ? sc[t - off] : 0;
        __syncthreads();
        sc[t] += a;
    }
    __syncthreads();
    int off = sc[t] - tot;   // exclusive across thread groups
    int run = 0;
#pragma unroll
    for (int k = 0; k < 4; ++k) {
        int i = base + k;
        if (i < NB) { int p = off + run; bptr[i] = p; bcursor[i] = p; }
        run += v[k];
    }
    if (t == 255) bptr[NB] = sc[255];
}

// ---------------- P3: chunk-aggregated partition scatter ----------------
__global__ __launch_bounds__(256) void part_k(const int* __restrict__ row,
                                              const int* __restrict__ col, int E,
                                              int* __restrict__ bcursor,
                                              int* __restrict__ ebuf, int NB) {
    __shared__ int h[NBMAX];
    __shared__ int cur[NBMAX];
    int t = threadIdx.x;
    int start = blockIdx.x * PCHUNK;
    int end   = min(start + PCHUNK, E);
    for (int i = t; i < NB; i += 256) h[i] = 0;
    __syncthreads();
    for (int e = start + t; e < end; e += 256)
        atomicAdd(&h[col[e] / CPB], 1);
    __syncthreads();
    for (int i = t; i < NB; i += 256)
        cur[i] = h[i] ? atomicAdd(&bcursor[i], h[i]) : 0;
    __syncthreads();
    for (int e = start + t; e < end; e += 256) {
        int c = col[e], b = c / CPB, cl = c - b * CPB;
        int pos = atomicAdd(&cur[b], 1);
        ebuf[pos] = row[e] | (cl << 17);   // row < 2^17, cl < 2^8
    }
}

// ---------------- P4: counting sort -> per-node CSR (row-only) + dinv ----------------
__global__ __launch_bounds__(256) void sort_k(const int* __restrict__ ebuf,
                                              const int* __restrict__ bptr,
                                              float* __restrict__ dinv,
                                              int* __restrict__ ptrv, int* __restrict__ cnt,
                                              int* __restrict__ csr, int N) {
    __shared__ int h[CPB];
    __shared__ int cur[CPB];
    __shared__ int sc[256];
    int b = blockIdx.x, t = threadIdx.x;
    for (int i = t; i < CPB; i += 256) h[i] = 0;
    __syncthreads();
    int s = bptr[b], e = bptr[b + 1];
    for (int j = s + t; j < e; j += 256)
        atomicAdd(&h[ebuf[j] >> 17], 1);
    __syncthreads();
    int v = (t < CPB) ? h[t] : 0;
    sc[t] = v;
    for (int off = 1; off < 256; off <<= 1) {
        __syncthreads();
        int a = (t >= off) ? sc[t - off] : 0;
        __syncthreads();
        sc[t] += a;
    }
    __syncthreads();
    if (t < CPB) {
        int c = b * CPB + t;
        int p = s + sc[t] - v;
        cur[t] = p;
        if (c < N) {
            ptrv[c] = p; cnt[c] = v;
            dinv[c] = rsqrtf((float)(v + 1));   // +1: self-loop
        }
    }
    __syncthreads();
    for (int j = s + t; j < e; j += 256) {
        int p = ebuf[j];
        int pos = atomicAdd(&cur[p >> 17], 1);
        csr[pos] = p & 0x1FFFF;
    }
}

// ---------------- projection: z0 = fp16( dinv ⊙ (x @ W^T) ) ----------------
__global__ __launch_bounds__(256) void proj_k(const float* __restrict__ x,
                                              const float* __restrict__ W,
                                              const float* __restrict__ dinv,
                                              __half* __restrict__ z, int n) {
    __shared__ float xs[64][132];
    __shared__ float ws[128][68];
    int t = threadIdx.x;
    int nb = blockIdx.x * 64;

    for (int it = 0; it < 8; ++it) {
        int chunk = t + it * 256;
        int c  = chunk >> 5;
        int f4 = (chunk & 31) << 2;
        float4 wv = *reinterpret_cast<const float4*>(&W[c * NFEAT + f4]);
        ws[f4 + 0][c] = wv.x; ws[f4 + 1][c] = wv.y;
        ws[f4 + 2][c] = wv.z; ws[f4 + 3][c] = wv.w;
    }
    for (int it = 0; it < 8; ++it) {
        int chunk = t + it * 256;
        int nloc = chunk >> 5;
        int f4   = (chunk & 31) << 2;
        int g = nb + nloc;
        float4 xv = (g < n) ? *reinterpret_cast<const float4*>(&x[(size_t)g * NFEAT + f4])
                            : make_float4(0.f, 0.f, 0.f, 0.f);
        *reinterpret_cast<float4*>(&xs[nloc][f4]) = xv;
    }
    __syncthreads();

    int tc = t & 15;
    int tn = t >> 4;
    float4 acc[4];
#pragma unroll
    for (int i = 0; i < 4; ++i) acc[i] = make_float4(0.f, 0.f, 0.f, 0.f);

    for (int f4 = 0; f4 < NFEAT; f4 += 4) {
        float4 xv[4], wv[4];
#pragma unroll
        for (int i = 0; i < 4; ++i)
            xv[i] = *reinterpret_cast<const float4*>(&xs[tn + 16 * i][f4]);
#pragma unroll
        for (int k = 0; k < 4; ++k)
            wv[k] = *reinterpret_cast<const float4*>(&ws[f4 + k][tc * 4]);
#pragma unroll
        for (int i = 0; i < 4; ++i) {
            acc[i].x += xv[i].x * wv[0].x + xv[i].y * wv[1].x + xv[i].z * wv[2].x + xv[i].w * wv[3].x;
            acc[i].y += xv[i].x * wv[0].y + xv[i].y * wv[1].y + xv[i].z * wv[2].y + xv[i].w * wv[3].y;
            acc[i].z += xv[i].x * wv[0].z + xv[i].y * wv[1].z + xv[i].z * wv[2].z + xv[i].w * wv[3].z;
            acc[i].w += xv[i].x * wv[0].w + xv[i].y * wv[1].w + xv[i].z * wv[2].w + xv[i].w * wv[3].w;
        }
    }
#pragma unroll
    for (int i = 0; i < 4; ++i) {
        int g = nb + tn + 16 * i;
        if (g < n) {
            float d = dinv[g];
            __half2 h0 = __floats2half2_rn(acc[i].x * d, acc[i].y * d);
            __half2 h1 = __floats2half2_rn(acc[i].z * d, acc[i].w * d);
            uint2 pk;
            pk.x = *reinterpret_cast<unsigned int*>(&h0);
            pk.y = *reinterpret_cast<unsigned int*>(&h1);
            *reinterpret_cast<uint2*>(&z[(size_t)g * NCLS + tc * 4]) = pk;
        }
    }
}

// ---------------- P5: SpMM hop on fp16 z, 8 edges/wave-instruction ----------------
// lane = 8*edge_slot + class_octet; 16B/lane (8 halves), fp32 accumulate.
// FINAL=0: z1 = fp16( d^2 * (self + sum) );  FINAL=1: out_f32 = d*(self+sum) + bias.
template <int FINAL>
__global__ __launch_bounds__(256) void spmm_k(const __half* __restrict__ zin,
                                              void* __restrict__ outp,
                                              const int* __restrict__ ptrv,
                                              const int* __restrict__ cnt,
                                              const float* __restrict__ dinv,
                                              const int* __restrict__ csr,
                                              const float* __restrict__ bias, int n) {
    int t = threadIdx.x;
    int lane = t & 63;
    int wid  = blockIdx.x * 4 + (t >> 6);
    wid = __builtin_amdgcn_readfirstlane(wid);
    if (wid >= n) return;

    int sub = lane >> 3;        // edge slot 0..7
    int cg  = (lane & 7) * 8;   // class octet base (halves)
    int s = ptrv[wid];
    int e = s + cnt[wid];

    float a[8];
#pragma unroll
    for (int k = 0; k < 8; ++k) a[k] = 0.f;

#define ACCUM(u)                                                            \
    {                                                                       \
        __half2 t0 = *reinterpret_cast<const __half2*>(&u.x);               \
        __half2 t1 = *reinterpret_cast<const __half2*>(&u.y);               \
        __half2 t2 = *reinterpret_cast<const __half2*>(&u.z);               \
        __half2 t3 = *reinterpret_cast<const __half2*>(&u.w);               \
        float2 f0 = __half22float2(t0), f1 = __half22float2(t1);            \
        float2 f2 = __half22float2(t2), f3 = __half22float2(t3);            \
        a[0] += f0.x; a[1] += f0.y; a[2] += f1.x; a[3] += f1.y;             \
        a[4] += f2.x; a[5] += f2.y; a[6] += f3.x; a[7] += f3.y;             \
    }

    int j = s;
    for (; j + 16 <= e; j += 16) {
        int r0 = csr[j + sub];
        int r1 = csr[j + 8 + sub];
        uint4 g0 = *reinterpret_cast<const uint4*>(&zin[(size_t)r0 * NCLS + cg]);
        uint4 g1 = *reinterpret_cast<const uint4*>(&zin[(size_t)r1 * NCLS + cg]);
        ACCUM(g0); ACCUM(g1);
    }
    if (j + 8 <= e) {
        int r0 = csr[j + sub];
        uint4 g0 = *reinterpret_cast<const uint4*>(&zin[(size_t)r0 * NCLS + cg]);
        ACCUM(g0);
        j += 8;
    }
    if (j + sub < e) {           // 1..7 leftover edges
        int r0 = csr[j + sub];
        uint4 g0 = *reinterpret_cast<const uint4*>(&zin[(size_t)r0 * NCLS + cg]);
        ACCUM(g0);
    }

    // reduce the 8 edge slots (lane bits 3,4,5)
#pragma unroll
    for (int m = 8; m <= 32; m <<= 1)
#pragma unroll
        for (int k = 0; k < 8; ++k)
            a[k] += __shfl_xor(a[k], m, 64);

    // self term (all lanes load; post-reduction add so it counts once)
    uint4 sv = *reinterpret_cast<const uint4*>(&zin[(size_t)wid * NCLS + cg]);
    ACCUM(sv);
#undef ACCUM

    float d = dinv[wid];
    if (FINAL) {
        float* out = (float*)outp;
        float4 b0 = *reinterpret_cast<const float4*>(&bias[cg]);
        float4 b1 = *reinterpret_cast<const float4*>(&bias[cg + 4]);
        if (sub == 0) {
            float4 o0, o1;
            o0.x = fmaf(d, a[0], b0.x); o0.y = fmaf(d, a[1], b0.y);
            o0.z = fmaf(d, a[2], b0.z); o0.w = fmaf(d, a[3], b0.w);
            o1.x = fmaf(d, a[4], b1.x); o1.y = fmaf(d, a[5], b1.y);
            o1.z = fmaf(d, a[6], b1.z); o1.w = fmaf(d, a[7], b1.w);
            *reinterpret_cast<float4*>(&out[(size_t)wid * NCLS + cg])     = o0;
            *reinterpret_cast<float4*>(&out[(size_t)wid * NCLS + cg + 4]) = o1;
        }
    } else {
        __half* zo = (__half*)outp;
        float d2 = d * d;
        if (sub == 0) {
            __half2 h0 = __floats2half2_rn(d2 * a[0], d2 * a[1]);
            __half2 h1 = __floats2half2_rn(d2 * a[2], d2 * a[3]);
            __half2 h2 = __floats2half2_rn(d2 * a[4], d2 * a[5]);
            __half2 h3 = __floats2half2_rn(d2 * a[6], d2 * a[7]);
            uint4 pk;
            pk.x = *reinterpret_cast<unsigned int*>(&h0);
            pk.y = *reinterpret_cast<unsigned int*>(&h1);
            pk.z = *reinterpret_cast<unsigned int*>(&h2);
            pk.w = *reinterpret_cast<unsigned int*>(&h3);
            *reinterpret_cast<uint4*>(&zo[(size_t)wid * NCLS + cg]) = pk;
        }
    }
}

// ---------------- launch ----------------
extern "C" void kernel_launch(void* const* d_in, const int* in_sizes, int n_in,
                              void* d_out, int out_size, void* d_ws, size_t ws_size,
                              hipStream_t stream) {
    const float* x  = (const float*)d_in[0];
    const int*   ei = (const int*)d_in[1];
    const float* W  = (const float*)d_in[2];
    const float* b  = (const float*)d_in[3];

    const int N = in_sizes[0] / NFEAT;   // 100000
    const int E = in_sizes[1] / 2;       // 1600000
    const int* row = ei;
    const int* col = ei + E;
    const int NB = (N + CPB - 1) / CPB;  // 521
    if (NB + 1 > NBMAX) return;

    // workspace layout
    __half* z0     = (__half*)d_ws;                 // N*64 halves
    __half* z1     = z0 + (size_t)N * NCLS;         // N*64 halves
    int*   ebuf    = (int*)(z1 + (size_t)N * NCLS); // E
    int*   csr     = ebuf + E;                      // E
    float* dinv    = (float*)(csr + E);             // N
    int*   ptrv    = (int*)(dinv + N);              // N
    int*   cnt     = ptrv + N;                      // N
    int*   bhist   = cnt + N;                       // NB
    int*   done    = bhist + NB;                    // 1
    int*   bptr    = done + 1;                      // NB+1
    int*   bcursor = bptr + NB + 1;                 // NB

    size_t needed = (size_t)N * NCLS * 2 * 2
                  + ((size_t)E * 2 + (size_t)N * 3 + 3 * (size_t)NB + 2) * 4;
    if (ws_size < needed) return;

    hipMemsetAsync(bhist, 0, ((size_t)NB + 1) * 4, stream);   // bhist + done
    hist_k<<<HGRID, 256, 0, stream>>>(col, E, bhist, done, bptr, bcursor, NB);
    part_k<<<(E + PCHUNK - 1) / PCHUNK, 256, 0, stream>>>(row, col, E, bcursor, ebuf, NB);
    sort_k<<<NB, 256, 0, stream>>>(ebuf, bptr, dinv, ptrv, cnt, csr, N);

    proj_k<<<(N + 63) / 64, 256, 0, stream>>>(x, W, dinv, z0, N);

    spmm_k<0><<<(N + 3) / 4, 256, 0, stream>>>(z0, (void*)z1,  ptrv, cnt, dinv, csr, b, N);
    spmm_k<1><<<(N + 3) / 4, 256, 0, stream>>>(z1, d_out,      ptrv, cnt, dinv, csr, b, N);
}